// Round 10
// baseline (309.091 us; speedup 1.0000x reference)
//
#include <hip/hip_runtime.h>
#include <math.h>

#define HID 256
#define SEQ 512

typedef _Float16 half8 __attribute__((ext_vector_type(8)));
typedef _Float16 half4 __attribute__((ext_vector_type(4)));
typedef float    f32x4 __attribute__((ext_vector_type(4)));

// ---------------------------------------------------------------------------
// Phase 1: inp[t][i] = b[i] + sum_j emb[idx[t]][j] * W[i][HID + j]   (all f32)
// ---------------------------------------------------------------------------
__global__ __launch_bounds__(256) void qrnn_phase1(
    const int* __restrict__ idx, const float* __restrict__ emb,
    const float* __restrict__ W, const float* __restrict__ b,
    float* __restrict__ inp)
{
    const int t = blockIdx.x;
    const int i = threadIdx.x;
    __shared__ float xs[HID];
    const size_t row = (size_t)idx[t];
    xs[i] = emb[row * HID + i];
    __syncthreads();

    const float* wr = W + (size_t)i * (2 * HID) + HID;  // Wx row i
    float acc = b[i];
#pragma unroll
    for (int k = 0; k < HID / 4; ++k) {
        const float4 w4 = *reinterpret_cast<const float4*>(wr + k * 4);
        const float4 x4 = *reinterpret_cast<const float4*>(&xs[k * 4]);
        acc = fmaf(w4.x, x4.x, acc);
        acc = fmaf(w4.y, x4.y, acc);
        acc = fmaf(w4.z, x4.z, acc);
        acc = fmaf(w4.w, x4.w, acc);
    }
    inp[t * HID + i] = acc;
}

// Pin a half8 into an AGPR quad: MFMA reads A directly from AGPRs (no copy),
// and an asm-defined value cannot be rematerialized from its load. This
// aligns with the allocator's proven preference (rounds 3-9: it parks large
// loop-invariant tiles in AGPRs no matter what) instead of fighting it.
#define PIN_A(x) asm volatile("" : "+a"(x))

// ---------------------------------------------------------------------------
// Phase 2: sequential scan on the MFMA pipe. 256 threads = 4 waves, 1/SIMD.
// Wave w owns output rows [64w, 64w+64) as 4 row-tiles (rt) of 16.
// Per step: D_rt(16x16) = sum_{kc=0..7} A_rt,kc(16x32) * B_kc(32x16), where
//   A_rt,kc = Wh[64w+16rt .. +16][32kc .. +32]  (f16, resident in AGPRs)
//   B_kc    = h[32kc .. +32] BROADCAST into all 16 columns.
// Broadcast-B makes B's column mapping irrelevant, and any error in the
// assumed k-enumeration cancels because A and B fragments use the same
// (lane>>4, elem) -> k order (dot products are permutation-invariant).
// C/D layout (HW-verified, m89): col = lane&15, row = (lane>>4)*4 + reg.
// So every lane holds 4 y-values (rows 4q+j of its rt copies across cols);
// lanes with col c < 4 own rt = c: add inp, tanh, pack f16, ds_write_b64.
// h double-buffered in LDS as f16[256] (512 B); one barrier per step.
// MFMA issue: 32 x ~5 cy = 160 cy/SIMD/step; VALU epilogue ~110 cy.
// ---------------------------------------------------------------------------
__global__ __launch_bounds__(256) void qrnn_phase2(
    const float* __restrict__ W, const float* __restrict__ inp,
    float* __restrict__ out)
{
    const int tid  = threadIdx.x;
    const int wave = tid >> 6;          // [0,4)
    const int l    = tid & 63;
    const int c    = l & 15;            // D column this lane holds
    const int q    = l >> 4;            // D row-quad selector
    const int rbase = 64 * wave;        // wave's first output row

    __shared__ __align__(16) _Float16 hbuf[2][HID];
    hbuf[0][tid] = (_Float16)0.0f;      // h0 = 0 (all 256 slots)

    // ---- A fragments: af[rt][kc], elem j = Wh[rbase+16rt+c][32kc+8q+j] ----
    half8 af[4][8];
#pragma unroll
    for (int rt = 0; rt < 4; ++rt) {
#pragma unroll
        for (int kc = 0; kc < 8; ++kc) {
            const float* wr =
                W + (size_t)(rbase + 16 * rt + c) * (2 * HID) + 32 * kc + 8 * q;
            half8 v;
#pragma unroll
            for (int j = 0; j < 8; ++j) v[j] = (_Float16)wr[j];
            af[rt][kc] = v;
            PIN_A(af[rt][kc]);
        }
    }

    // ip prefetch: lane (c<4, q) epilogue-owns rows rbase+16c+4q..+3.
    // All lanes load (c&3 keeps addresses valid); only c<4 lanes use it.
    const int iprow = rbase + 16 * (c & 3) + 4 * q;
    f32x4 ipv = *reinterpret_cast<const f32x4*>(inp + iprow);

    f32x4 hout = {0.0f, 0.0f, 0.0f, 0.0f};
    __syncthreads();

    auto step = [&](const _Float16* __restrict__ src,
                    _Float16* __restrict__ dst, int tnext) {
        // B fragments: bf[kc][j] = h[32kc + 8q + j] (broadcast across 16
        // lanes of each q-group -> conflict-free ds_read_b128)
        half8 bf[8];
#pragma unroll
        for (int kc = 0; kc < 8; ++kc)
            bf[kc] = *reinterpret_cast<const half8*>(src + 32 * kc + 8 * q);

        // Prefetch next step's inp under the MFMAs
        f32x4 ip_next = *reinterpret_cast<const f32x4*>(
            inp + (size_t)(tnext & (SEQ - 1)) * HID + iprow);

        // 32 MFMAs: 4 independent row-tile chains, 8 K-chunks each
        f32x4 acc[4];
#pragma unroll
        for (int rt = 0; rt < 4; ++rt) acc[rt] = (f32x4){0.f, 0.f, 0.f, 0.f};
#pragma unroll
        for (int kc = 0; kc < 8; ++kc) {
#pragma unroll
            for (int rt = 0; rt < 4; ++rt)
                acc[rt] = __builtin_amdgcn_mfma_f32_16x16x32_f16(
                    af[rt][kc], bf[kc], acc[rt], 0, 0, 0);
        }

        // Lane's tile: rt = c (valid for c<4); every column of D equals y,
        // so this lane's 4 regs are y[rbase+16c+4q .. +3]
        f32x4 m01 = (c & 1) ? acc[1] : acc[0];
        f32x4 m23 = (c & 1) ? acc[3] : acc[2];
        f32x4 mine = (c & 2) ? m23 : m01;

        f32x4 d = mine + ipv;
        f32x4 hN;
#pragma unroll
        for (int j = 0; j < 4; ++j) {
            float e = __expf(2.0f * d[j]);       // tanh = 1 - 2/(e^(2d)+1)
            hN[j] = 1.0f - 2.0f / (e + 1.0f);
        }
        hout = hN;

        if (c < 4) {
            half4 hh = { (_Float16)hN[0], (_Float16)hN[1],
                         (_Float16)hN[2], (_Float16)hN[3] };
            *reinterpret_cast<half4*>(dst + rbase + 16 * c + 4 * q) = hh;
        }

        ipv = ip_next;
        __syncthreads();
    };

#pragma unroll 1
    for (int t = 0; t < SEQ; t += 2) {
        step(&hbuf[0][0], &hbuf[1][0], t + 1);
        step(&hbuf[1][0], &hbuf[0][0], t + 2);
    }

    // Final h (f32, pre-f16-rounding) from the last step's owners
    if (c < 4) {
        *reinterpret_cast<float4*>(out + rbase + 16 * c + 4 * q) =
            (float4){ hout[0], hout[1], hout[2], hout[3] };
    }
}

extern "C" void kernel_launch(void* const* d_in, const int* in_sizes, int n_in,
                              void* d_out, int out_size, void* d_ws, size_t ws_size,
                              hipStream_t stream)
{
    const int*   idx = (const int*)d_in[0];
    const float* emb = (const float*)d_in[1];
    const float* W   = (const float*)d_in[2];
    const float* b   = (const float*)d_in[3];
    float* out = (float*)d_out;
    float* inp = (float*)d_ws;  // SEQ*HID*4 = 512 KB scratch

    qrnn_phase1<<<SEQ, HID, 0, stream>>>(idx, emb, W, b, inp);
    qrnn_phase2<<<1, 256, 0, stream>>>(W, inp, out);
}